// Round 10
// baseline (203.400 us; speedup 1.0000x reference)
//
#include <hip/hip_runtime.h>

typedef int v4i __attribute__((ext_vector_type(4)));

constexpr int Kdim = 4096;
constexpr int Ndim = 4096;
constexpr int MtotC = 8192;
constexpr int BM = 128;
constexpr int BN = 256;
constexpr int BKB = 64;           // K-bytes per LDS tile
constexpr int NT = Kdim / BKB;    // 64 K-tiles

// ---------------- pack int32 -> int8 (both tensors, one launch) ----------------
__global__ void pack_i32_to_i8(const int* __restrict__ xq, const int* __restrict__ wq,
                               signed char* __restrict__ x8, signed char* __restrict__ w8,
                               size_t nx4, size_t nw4) {
    size_t i = (size_t)blockIdx.x * blockDim.x + threadIdx.x;
    size_t stride = (size_t)gridDim.x * blockDim.x;
    size_t tot = nx4 + nw4;
    for (size_t j = i; j < tot; j += stride) {
        if (j < nx4) {
            const int4 v = ((const int4*)xq)[j];
            char4 c;
            c.x = (signed char)v.x; c.y = (signed char)v.y;
            c.z = (signed char)v.z; c.w = (signed char)v.w;
            ((char4*)x8)[j] = c;
        } else {
            const size_t k = j - nx4;
            const int4 v = ((const int4*)wq)[k];
            char4 c;
            c.x = (signed char)v.x; c.y = (signed char)v.y;
            c.z = (signed char)v.z; c.w = (signed char)v.w;
            ((char4*)w8)[k] = c;
        }
    }
}

// ---------------- int8 GEMM, 128x256 tile, 4 waves, 2 blocks/CU ----------------
// LDS: 2 bufs x (A 8KB + B 16KB) = 48KB static -> 2 blocks/CU; cross-block TLP
// covers barrier/stage drains (barriers only couple 4 waves).
// 16B-slot swizzle within a 64B row: slot' = slot ^ ((row>>1)&3)  (verified 0-conflict).
__global__ __launch_bounds__(256, 2) void i8gemm_kernel(
    const signed char* __restrict__ A,
    const signed char* __restrict__ W,
    const float* __restrict__ sx,
    const float* __restrict__ wsc,
    const float* __restrict__ bias,
    float* __restrict__ C)
{
    __shared__ signed char smem[2][24576];   // [buf][A 8KB | B 16KB]

    const int tid  = threadIdx.x;
    const int wave = tid >> 6;
    const int lane = tid & 63;
    const int wr = wave >> 1;     // 0..1  (64-row strip)
    const int wc = wave & 1;      // 0..1  (128-col strip)

    // XCD-aware bijective swizzle: 1024 wgs, 8 regions of 16bm x 8bn (8MB A + 8MB B each)
    const int xcd = blockIdx.x & 7;
    const int idx = blockIdx.x >> 3;          // 0..127
    const int bm = ((xcd & 3) * 16 + (idx & 15)) * BM;
    const int bn = ((xcd >> 2) * 8 + (idx >> 4)) * BN;

    // ---- staging constants ----
    // LDS dest is exactly tid*16 within each 4KB row-block (linear, gload_lds-safe).
    const int srow4 = tid >> 2;                        // 0..63 (row within 64-row block)
    const int gslot = (tid & 3) ^ ((tid >> 3) & 3);    // pre-inverse-swizzled global 16B slot
    const signed char* Ag = A + (size_t)(bm + srow4) * Kdim + gslot * 16;
    const signed char* Wg = W + (size_t)(bn + srow4) * Kdim + gslot * 16;

    // ---- fragment read constants (16x16x64: row/col = lane&15, 16B k-slot = lane>>4) ----
    const int frow = lane & 15;
    const int fsl  = lane >> 4;
    const int rsw  = ((fsl ^ ((frow >> 1) & 3)) << 4);       // swizzled 16B slot byte
    const int aro  = (wr * 64 + frow) * 64 + rsw;            // + f*1024
    const int bro  = 8192 + (wc * 128 + frow) * 64 + rsw;    // + g*1024

    v4i acc[4][8];
#pragma unroll
    for (int f = 0; f < 4; ++f)
#pragma unroll
        for (int g = 0; g < 8; ++g)
#pragma unroll
            for (int e = 0; e < 4; ++e) acc[f][g][e] = 0;

    // 6 global_load_lds per thread per K-tile (2 A-blocks + 4 B-blocks of 64 rows)
#define STG(KT) do {                                                                   \
    signed char* dst = &smem[(KT) & 1][0];                                             \
    const size_t ko = (size_t)(KT) * BKB;                                              \
    _Pragma("unroll") for (int r = 0; r < 2; ++r)                                      \
        __builtin_amdgcn_global_load_lds(                                              \
            (const __attribute__((address_space(1))) void*)(Ag + (size_t)(r * 64) * Kdim + ko), \
            (__attribute__((address_space(3))) void*)(dst + r * 4096 + tid * 16), 16, 0, 0);    \
    _Pragma("unroll") for (int rb = 0; rb < 4; ++rb)                                   \
        __builtin_amdgcn_global_load_lds(                                              \
            (const __attribute__((address_space(1))) void*)(Wg + (size_t)(rb * 64) * Kdim + ko), \
            (__attribute__((address_space(3))) void*)(dst + 8192 + rb * 4096 + tid * 16), 16, 0, 0); \
} while (0)

#define BAR __builtin_amdgcn_s_barrier()

    // ---- prologue: stage tiles 0,1 (12 loads/thread); drain tile 0 ----
    STG(0);
    STG(1);
    asm volatile("s_waitcnt vmcnt(6)" ::: "memory");
    BAR;

    for (int u = 0; u < NT; ++u) {
        const signed char* bufb = &smem[u & 1][0];

        // 12 ds_read_b128 + 32 MFMA; compiler interleaves fine-grained lgkmcnt
        v4i av[4], bv[8];
#pragma unroll
        for (int g = 0; g < 8; ++g) bv[g] = *(const v4i*)(bufb + bro + g * 1024);
#pragma unroll
        for (int f = 0; f < 4; ++f) av[f] = *(const v4i*)(bufb + aro + f * 1024);

        __builtin_amdgcn_s_setprio(1);
#pragma unroll
        for (int f = 0; f < 4; ++f)
#pragma unroll
            for (int g = 0; g < 8; ++g)
                acc[f][g] = __builtin_amdgcn_mfma_i32_16x16x64_i8(av[f], bv[g], acc[f][g], 0, 0, 0);
        __builtin_amdgcn_s_setprio(0);

        BAR;   // all 4 waves done reading buf[u&1]

        if (u + 2 < NT) {
            STG(u + 2);                                         // -> buf[u&1]
            asm volatile("s_waitcnt vmcnt(6)" ::: "memory");    // tile u+1 landed
            BAR;
        } else if (u + 1 < NT) {
            asm volatile("s_waitcnt vmcnt(0)" ::: "memory");    // last tile landed
            BAR;
        }
    }

    // ---- epilogue: dequant + bias, fp32 store ----
    // 16x16 C/D map: col = lane&15, row = (lane>>4)*4 + reg
    const int orow0 = bm + wr * 64;
    const int ocol0 = bn + wc * 128;
    float wsv[8], bvv[8];
#pragma unroll
    for (int g = 0; g < 8; ++g) {
        const int col = ocol0 + g * 16 + frow;
        wsv[g] = wsc[col];
        bvv[g] = bias[col];
    }
#pragma unroll
    for (int f = 0; f < 4; ++f) {
#pragma unroll
        for (int jr = 0; jr < 4; ++jr) {
            const int row = orow0 + f * 16 + fsl * 4 + jr;
            const float s = sx[row];
#pragma unroll
            for (int g = 0; g < 8; ++g) {
                const int col = ocol0 + g * 16 + frow;
                C[(size_t)row * Ndim + col] = (float)acc[f][g][jr] * s * wsv[g] + bvv[g];
            }
        }
    }
#undef STG
#undef BAR
}

extern "C" void kernel_launch(void* const* d_in, const int* in_sizes, int n_in,
                              void* d_out, int out_size, void* d_ws, size_t ws_size,
                              hipStream_t stream) {
    (void)in_sizes; (void)n_in; (void)out_size; (void)ws_size;
    const int*   x_q  = (const int*)d_in[0];
    const float* sx   = (const float*)d_in[1];
    const int*   w_q  = (const int*)d_in[2];
    const float* wsc  = (const float*)d_in[3];
    const float* bias = (const float*)d_in[4];
    float* out = (float*)d_out;

    signed char* x8 = (signed char*)d_ws;
    signed char* w8 = x8 + (size_t)MtotC * Kdim;

    const size_t nx = (size_t)MtotC * Kdim;   // 32 Mi
    const size_t nw = (size_t)Ndim * Kdim;    // 16 Mi

    pack_i32_to_i8<<<3072, 256, 0, stream>>>(x_q, w_q, x8, w8, nx / 4, nw / 4);

    const int nwg = (MtotC / BM) * (Ndim / BN);  // 64 * 16 = 1024
    i8gemm_kernel<<<nwg, 256, 0, stream>>>(x8, w8, sx, wsc, bias, out);
}